// Round 1
// baseline (1535.339 us; speedup 1.0000x reference)
//
#include <hip/hip_runtime.h>
#include <math.h>

#define N_DST   32768
#define N_EDGE  524288
#define LN_EPS  1e-5f

// ---------- prep: transpose wkv_w -> Wt[300][200], fold Q time-bias ----------
__global__ void k_prep(const float* __restrict__ wkv_w, const float* __restrict__ wq_w,
                       const float* __restrict__ wq_b, const float* __restrict__ time_b,
                       float* __restrict__ Wt, float* __restrict__ zq) {
    int idx = blockIdx.x * 256 + threadIdx.x;
    if (idx < 60000) {
        int k = idx / 200, o = idx % 200;
        Wt[idx] = wkv_w[o * 300 + k];
    } else if (idx < 60100) {
        int o = idx - 60000;
        float acc = wq_b[o];
        for (int j = 0; j < 100; ++j)
            acc += cosf(time_b[j]) * wq_w[o * 200 + 100 + j];
        zq[o] = acc;
    }
}

// ---------- CSR offsets via binary search over sorted edge_dst ----------
__global__ void k_offsets(const int* __restrict__ dst, int* __restrict__ off) {
    int n = blockIdx.x * 256 + threadIdx.x;
    if (n > N_DST) return;
    int lo = 0, hi = N_EDGE;
    while (lo < hi) {
        int mid = (lo + hi) >> 1;
        if (dst[mid] < n) lo = mid + 1; else hi = mid;
    }
    off[n] = lo;
}

// ---------- Q = dst_h @ wq_w[:, :100].T + zq ----------
__global__ __launch_bounds__(128) void k_q(const float* __restrict__ dst_h,
                                           const float* __restrict__ wq_w,
                                           const float* __restrict__ zq,
                                           float* __restrict__ Q) {
    int n = blockIdx.x, t = threadIdx.x;
    __shared__ float dl[100];
    if (t < 100) dl[t] = dst_h[n * 100 + t];
    __syncthreads();
    if (t < 100) {
        float acc = zq[t];
        const float* __restrict__ wr = wq_w + t * 200;
        #pragma unroll 4
        for (int i = 0; i < 100; ++i) acc = fmaf(dl[i], wr[i], acc);
        Q[n * 100 + t] = acc;
    }
}

// ---------- big edge kernel: Z = X @ Wt (+b), attn logits, V writeout ----------
// block: 64 edges, dim (64,8). wave w owns outputs [25w, 25w+25); lane = edge.
__global__ __launch_bounds__(512, 4) void k_edge(
        const float* __restrict__ src_h, const float* __restrict__ efeat,
        const float* __restrict__ td,    const int* __restrict__ edge_dst,
        const float* __restrict__ time_w, const float* __restrict__ time_b,
        const float* __restrict__ Wt,    const float* __restrict__ wkv_b,
        const float* __restrict__ Q,
        float* __restrict__ Vbuf, float* __restrict__ attn) {
    __shared__ float Xs[64 * 301];          // 77,056 B; also reused as Zs[64][201]
    const int e0 = blockIdx.x * 64;
    const int t  = threadIdx.y * 64 + threadIdx.x;

    // stage src_h / efeat (perfectly coalesced float4: addr = base + idx*16)
    const float4* s4 = (const float4*)(src_h + (size_t)e0 * 100);
    const float4* f4 = (const float4*)(efeat + (size_t)e0 * 100);
    for (int idx = t; idx < 1600; idx += 512) {
        int e = idx / 25, q = idx % 25;
        float4 v = s4[idx];
        float* xr = Xs + e * 301 + q * 4;
        xr[0] = v.x; xr[1] = v.y; xr[2] = v.z; xr[3] = v.w;
        float4 u = f4[idx];
        float* xr2 = Xs + e * 301 + 100 + q * 4;
        xr2[0] = u.x; xr2[1] = u.y; xr2[2] = u.z; xr2[3] = u.w;
    }
    // time features
    for (int idx = t; idx < 6400; idx += 512) {
        int e = idx / 100, k = idx % 100;
        Xs[e * 301 + 200 + k] = cosf(td[e0 + e] * time_w[k] + time_b[k]);
    }
    __syncthreads();

    const int lane = threadIdx.x;
    const int w    = __builtin_amdgcn_readfirstlane(threadIdx.y);
    const int ob   = w * 25;                 // wave-uniform output base

    float acc[25];
    #pragma unroll
    for (int oo = 0; oo < 25; ++oo) acc[oo] = wkv_b[ob + oo];

    const float* __restrict__ xrow = Xs + lane * 301;
    for (int k = 0; k < 300; ++k) {
        float x = xrow[k];
        const float* __restrict__ wr = Wt + k * 200 + ob;   // wave-uniform -> s_load
        #pragma unroll
        for (int oo = 0; oo < 25; ++oo) acc[oo] = fmaf(x, wr[oo], acc[oo]);
    }
    __syncthreads();                        // done reading Xs

    float* Zs = Xs;                         // Zs[e][o], stride 201 (conflict-free)
    #pragma unroll
    for (int oo = 0; oo < 25; ++oo) Zs[lane * 201 + ob + oo] = acc[oo];
    __syncthreads();

    // attn logits: t<128 -> (edge, head)
    if (t < 128) {
        int e = t & 63, h = t >> 6;
        int edge = e0 + e;
        const float* __restrict__ q  = Q + (size_t)edge_dst[edge] * 100 + h * 50;
        const float* __restrict__ kk = Zs + e * 201 + h * 50;
        float s = 0.f;
        #pragma unroll 5
        for (int d = 0; d < 50; ++d) s = fmaf(q[d], kk[d], s);
        s = s > 0.f ? s : 0.2f * s;         // leaky_relu(0.2)
        attn[(size_t)edge * 2 + h] = s;
    }
    // V writeout (coalesced: addr = e0*100 + idx)
    for (int idx = t; idx < 6400; idx += 512) {
        int e = idx / 100, j = idx % 100;
        Vbuf[(size_t)e0 * 100 + idx] = Zs[e * 201 + 100 + j];
    }
}

// ---------- segment softmax + weighted V reduce ----------
__global__ __launch_bounds__(128) void k_soft(const float* __restrict__ attn,
                                              const float* __restrict__ V,
                                              const int* __restrict__ off,
                                              float* __restrict__ agg) {
    int n = blockIdx.x, t = threadIdx.x;
    int r0 = off[n], cnt = off[n + 1] - r0;
    __shared__ float red0[128], red1[128], p0[128], p1[128];
    if (cnt <= 0) { if (t < 100) agg[n * 100 + t] = 0.f; return; }

    float m0 = -1e30f, m1 = -1e30f;
    for (int i = t; i < cnt; i += 128) {
        m0 = fmaxf(m0, attn[(size_t)(r0 + i) * 2]);
        m1 = fmaxf(m1, attn[(size_t)(r0 + i) * 2 + 1]);
    }
    red0[t] = m0; red1[t] = m1; __syncthreads();
    for (int s = 64; s > 0; s >>= 1) {
        if (t < s) { red0[t] = fmaxf(red0[t], red0[t + s]); red1[t] = fmaxf(red1[t], red1[t + s]); }
        __syncthreads();
    }
    m0 = red0[0]; m1 = red1[0]; __syncthreads();

    float s0 = 0.f, s1 = 0.f;
    for (int i = t; i < cnt; i += 128) {
        s0 += expf(attn[(size_t)(r0 + i) * 2]     - m0);
        s1 += expf(attn[(size_t)(r0 + i) * 2 + 1] - m1);
    }
    red0[t] = s0; red1[t] = s1; __syncthreads();
    for (int s = 64; s > 0; s >>= 1) {
        if (t < s) { red0[t] += red0[t + s]; red1[t] += red1[t + s]; }
        __syncthreads();
    }
    float inv0 = 1.f / red0[0], inv1 = 1.f / red1[0];
    __syncthreads();

    float acc = 0.f;
    for (int base = 0; base < cnt; base += 128) {
        int i = base + t;
        __syncthreads();
        if (i < cnt) {
            p0[t] = expf(attn[(size_t)(r0 + i) * 2]     - m0) * inv0;
            p1[t] = expf(attn[(size_t)(r0 + i) * 2 + 1] - m1) * inv1;
        }
        __syncthreads();
        int lim = min(128, cnt - base);
        if (t < 100) {
            const float* pp = (t < 50) ? p0 : p1;
            for (int j = 0; j < lim; ++j)
                acc = fmaf(pp[j], V[(size_t)(r0 + base + j) * 100 + t], acc);
        }
    }
    if (t < 100) agg[n * 100 + t] = acc;
}

// ---------- out proj + relu + layernorm ----------
__global__ __launch_bounds__(128) void k_out(const float* __restrict__ agg,
                                             const float* __restrict__ dst_h,
                                             const float* __restrict__ wout_w,
                                             const float* __restrict__ wout_b,
                                             const float* __restrict__ ln_g,
                                             const float* __restrict__ ln_b,
                                             float* __restrict__ out) {
    int n = blockIdx.x, t = threadIdx.x;
    __shared__ float al[100], dl[100], red[128];
    if (t < 100) { al[t] = agg[n * 100 + t]; dl[t] = dst_h[n * 100 + t]; }
    __syncthreads();
    float v = 0.f;
    if (t < 100) {
        float acc = wout_b[t];
        const float* __restrict__ wr = wout_w + t * 200;
        #pragma unroll 4
        for (int i = 0; i < 100; ++i) acc = fmaf(al[i], wr[i], acc);
        #pragma unroll 4
        for (int i = 0; i < 100; ++i) acc = fmaf(dl[i], wr[100 + i], acc);
        v = fmaxf(acc, 0.f);
    }
    red[t] = (t < 100) ? v : 0.f; __syncthreads();
    for (int s = 64; s > 0; s >>= 1) { if (t < s) red[t] += red[t + s]; __syncthreads(); }
    float mu = red[0] * 0.01f; __syncthreads();
    float dv = (t < 100) ? (v - mu) : 0.f;
    red[t] = dv * dv; __syncthreads();
    for (int s = 64; s > 0; s >>= 1) { if (t < s) red[t] += red[t + s]; __syncthreads(); }
    float var = red[0] * 0.01f;
    if (t < 100)
        out[n * 100 + t] = (v - mu) * rsqrtf(var + LN_EPS) * ln_g[t] + ln_b[t];
}

extern "C" void kernel_launch(void* const* d_in, const int* in_sizes, int n_in,
                              void* d_out, int out_size, void* d_ws, size_t ws_size,
                              hipStream_t stream) {
    const float* dst_h   = (const float*)d_in[0];
    const float* src_h   = (const float*)d_in[1];
    const float* efeat   = (const float*)d_in[2];
    const float* td      = (const float*)d_in[3];
    const int*   edst    = (const int*)  d_in[4];
    const float* time_w  = (const float*)d_in[5];
    const float* time_b  = (const float*)d_in[6];
    const float* wq_w    = (const float*)d_in[7];
    const float* wq_b    = (const float*)d_in[8];
    const float* wkv_w   = (const float*)d_in[9];
    const float* wkv_b   = (const float*)d_in[10];
    const float* wout_w  = (const float*)d_in[11];
    const float* wout_b  = (const float*)d_in[12];
    const float* ln_g    = (const float*)d_in[13];
    const float* ln_b    = (const float*)d_in[14];
    float* out = (float*)d_out;

    char* ws = (char*)d_ws;
    size_t off = 0;
    auto carve = [&](size_t bytes) { char* p = ws + off; off = (off + bytes + 255) & ~(size_t)255; return p; };
    float* Q     = (float*)carve((size_t)N_DST * 100 * 4);
    float* attn  = (float*)carve((size_t)N_EDGE * 2 * 4);
    float* Vbuf  = (float*)carve((size_t)N_EDGE * 100 * 4);
    float* agg   = (float*)carve((size_t)N_DST * 100 * 4);
    float* Wt    = (float*)carve(300 * 200 * 4);
    float* zq    = (float*)carve(100 * 4);
    int*   offs  = (int*)  carve((size_t)(N_DST + 1) * 4);

    k_prep<<<(60100 + 255) / 256, 256, 0, stream>>>(wkv_w, wq_w, wq_b, time_b, Wt, zq);
    k_offsets<<<(N_DST + 1 + 255) / 256, 256, 0, stream>>>(edst, offs);
    k_q<<<N_DST, 128, 0, stream>>>(dst_h, wq_w, zq, Q);
    k_edge<<<N_EDGE / 64, dim3(64, 8), 0, stream>>>(src_h, efeat, td, edst, time_w, time_b,
                                                    Wt, wkv_b, Q, Vbuf, attn);
    k_soft<<<N_DST, 128, 0, stream>>>(attn, Vbuf, offs, agg);
    k_out<<<N_DST, 128, 0, stream>>>(agg, dst_h, wout_w, wout_b, ln_g, ln_b, out);
}